// Round 15
// baseline (67.149 us; speedup 1.0000x reference)
//
#include <hip/hip_runtime.h>
#include <hip/hip_bf16.h>

#define EMB   768
#define SEQ   1024
#define NBAT  4
#define MROWS 4096      // NBAT*SEQ
#define NHEAD 12
#define HD    64
#define WIN   16
#define QB    16
#define KB    64
#define LN_EPS 1e-5f

typedef __attribute__((ext_vector_type(8))) short bf16x8;
typedef __attribute__((ext_vector_type(4))) float f32x4;
typedef unsigned short u16;
typedef unsigned int   u32;

// ---------------- f32 <-> bf16 helpers ----------------
static __device__ inline u16 f2bf(float f) {
    union { float f; u32 u; } a; a.f = f;
    u32 u = a.u;
    u32 r = (u + 0x7fffu + ((u >> 16) & 1u)) >> 16;
    return (u16)r;
}
static __device__ inline float bf2f(u16 x) {
    union { u32 u; float f; } c; c.u = ((u32)x) << 16; return c.f;
}
static __device__ inline u32 cvt2(float lo, float hi) {
    __hip_bfloat162 t = __float22bfloat162_rn(float2{lo, hi});
    union { __hip_bfloat162 h; u32 u; } c; c.h = t; return c.u;
}
static __device__ inline bf16x8 pack8(float4 a, float4 b) {
    union { bf16x8 v; u32 w[4]; } r;
    r.w[0] = cvt2(a.x, a.y); r.w[1] = cvt2(a.z, a.w);
    r.w[2] = cvt2(b.x, b.y); r.w[3] = cvt2(b.z, b.w);
    return r.v;
}

// ---------------- cast f32 -> bf16 (WEIGHTS ONLY) + Vsum zero ----------------
#define WT4  147456u    // 768*768/4
__global__ __launch_bounds__(256) void cast_w(
    const float* __restrict__ wq, const float* __restrict__ wk, const float* __restrict__ wv,
    u16* __restrict__ Wbf, float* __restrict__ Vsum)
{
    u32 u = blockIdx.x * 256u + threadIdx.x;      // 0 .. 3*WT4-1
    if (u < NBAT * EMB) Vsum[u] = 0.f;            // re-zero each call (ws not re-poisoned)
    u32 which = u / WT4;
    u32 off = (u - which * WT4) * 4u;
    const float* src = which == 0 ? wq : (which == 1 ? wk : wv);
    float4 val = *(const float4*)(src + off);
    ushort4 o;
    o.x = f2bf(val.x); o.y = f2bf(val.y); o.z = f2bf(val.z); o.w = f2bf(val.w);
    *(ushort4*)(Wbf + (size_t)which * 589824u + off) = o;
}

// ---------------- bf16 MFMA GEMM: 64x128 tile, BK=64, A staged as RAW F32 ----------------
// r10-proven 2-phase protocol, verbatim sync structure. A is staged into LDS
// as f32 via global_load_lds (type-agnostic 16B copies) and converted to bf16
// at the fragment read (pack8, same RNE -> bit-identical results). W staged
// bf16 as before. STAGE = 4 A-chunks + 4 W-chunks per thread -> counted
// vmcnt(8) (validated in r11). A-swizzle: 16 slots/row, slot=(c&15)^(row&15);
// fragment reads are 2-way bank-aliased (free). z==2 epilogue folds Vsum.
#define GK 768
#define GN 768

static __device__ inline void gload_lds16(const void* g, void* l) {
    __builtin_amdgcn_global_load_lds((const __attribute__((address_space(1))) void*)g,
                                     (__attribute__((address_space(3))) void*)l, 16, 0, 0);
}

__global__ __launch_bounds__(256) void gemm_qkv(
    const float* __restrict__ qa, const float* __restrict__ ka, const float* __restrict__ va,
    const u16* __restrict__ Wbase,
    const float* __restrict__ bq, const float* __restrict__ bk, const float* __restrict__ bv,
    u16* __restrict__ Qb, u16* __restrict__ Kb, u16* __restrict__ Vb,
    float* __restrict__ Vsum)
{
    const int z = blockIdx.z;
    const float* Af = (z == 0) ? qa : ((z == 1) ? ka : va);
    const u16* W = Wbase + (size_t)z * (GN * GK);
    const float* bias = (z == 0) ? bq : ((z == 1) ? bk : bv);
    u16* Ob = (z == 0) ? Qb : ((z == 1) ? Kb : Vb);

    // XCD swizzle: 384 tiles/z, 48 contiguous per XCD (8 A-panels each)
    int id = blockIdx.y * 6 + blockIdx.x;
    int swz = (id & 7) * 48 + (id >> 3);
    const int bm = (swz / 6) * 64, bn = (swz % 6) * 128;

    const int tid = threadIdx.x, wave = tid >> 6, lane = tid & 63;

    __shared__ __align__(16) float Asf[2][64 * 64];   // A tile, f32 (16 KB x2)
    __shared__ __align__(16) u16   Bs[2][128 * 64];   // W tile, bf16 (16 KB x2)

    f32x4 acc[2][4];
#pragma unroll
    for (int i = 0; i < 2; ++i)
#pragma unroll
        for (int j = 0; j < 4; ++j) acc[i][j] = (f32x4){0.f, 0.f, 0.f, 0.f};

    const int wr = (wave >> 1) * 32, wc = (wave & 1) * 64;
    const int r0 = lane & 15, hk = lane >> 4;

    // A staging: 1024 chunks of 16B (4 f32); chunk c -> row = c>>4,
    // src slot = (c&15)^(row&15)
    int asrow[4], ascol[4];
#pragma unroll
    for (int j = 0; j < 4; ++j) {
        int c = j * 256 + tid;
        asrow[j] = c >> 4;
        ascol[j] = ((c & 15) ^ (asrow[j] & 15)) * 4;   // f32 index
    }
    // W staging: 512 chunks of 16B (8 bf16); chunk c -> row = c>>3,
    // src slot = (c&7)^(row&7)   (r10-verbatim)
    int brow[4], bcol[4];
#pragma unroll
    for (int j = 0; j < 4; ++j) {
        int c = (j & 1) * 256 + tid;     // W only needs 2 iters; reuse j&1
        brow[j] = c >> 3;
        bcol[j] = ((c & 7) ^ (brow[j] & 7)) * 8;
    }

#define GEMM_STAGE(buf, K0) do { \
    _Pragma("unroll") for (int j = 0; j < 4; ++j) \
        gload_lds16(Af + (size_t)(bm + asrow[j]) * GK + (K0) + ascol[j], \
                    &Asf[buf][(j * 256 + tid) * 4]); \
    _Pragma("unroll") for (int j = 0; j < 4; ++j) \
        gload_lds16(W + (size_t)(bn + brow[j]) * GK + (K0) + bcol[j], \
                    &Bs[buf][((j & 1) * 256 + tid) * 8 + (j >> 1) * 4096]); \
} while (0)
// NOTE: W buffer is 512 chunks = 2 groups of 256; j=0,1 -> first half rows
// (c = (j&1)*256+tid covers chunks 0..511 across j=0..1); j=2,3 duplicate
// the same c but write the second 4096-u16 half -- WRONG. Use explicit form:
#undef GEMM_STAGE
#define GEMM_STAGE(buf, K0) do { \
    _Pragma("unroll") for (int j = 0; j < 4; ++j) \
        gload_lds16(Af + (size_t)(bm + asrow[j]) * GK + (K0) + ascol[j], \
                    &Asf[buf][(j * 256 + tid) * 4]); \
    _Pragma("unroll") for (int j = 0; j < 2; ++j) { \
        int c = j * 256 + tid; \
        int rw = c >> 3; \
        int cw = ((c & 7) ^ (rw & 7)) * 8; \
        gload_lds16(W + (size_t)(bn + rw) * GK + (K0) + cw, \
                    &Bs[buf][c * 8]); \
        int c2 = c + 512; \
        int rw2 = c2 >> 3; \
        int cw2 = ((c2 & 7) ^ (rw2 & 7)) * 8; \
        gload_lds16(W + (size_t)(bn + rw2) * GK + (K0) + cw2, \
                    &Bs[buf][c2 * 8]); } \
} while (0)

#define GEMM_COMPUTE(buf) do { \
    bf16x8 af[2][2], bg[2][4]; \
    _Pragma("unroll") for (int kk = 0; kk < 2; ++kk) { \
        _Pragma("unroll") for (int i = 0; i < 2; ++i) { \
            int ra = wr + i * 16 + r0; \
            int cb = kk * 8 + hk * 2; \
            int sa0 = cb ^ (ra & 15), sa1 = (cb + 1) ^ (ra & 15); \
            float4 f0 = *(const float4*)&Asf[buf][ra * 64 + sa0 * 4]; \
            float4 f1 = *(const float4*)&Asf[buf][ra * 64 + sa1 * 4]; \
            af[kk][i] = pack8(f0, f1); } \
        _Pragma("unroll") for (int j = 0; j < 4; ++j) { \
            int rb = wc + j * 16 + r0; int sb = (kk * 4 + hk) ^ (rb & 7); \
            bg[kk][j] = *(const bf16x8*)&Bs[buf][rb * 64 + sb * 8]; } } \
    _Pragma("unroll") for (int kk = 0; kk < 2; ++kk) \
    _Pragma("unroll") for (int i = 0; i < 2; ++i) \
    _Pragma("unroll") for (int j = 0; j < 4; ++j) \
        acc[i][j] = __builtin_amdgcn_mfma_f32_16x16x32_bf16(af[kk][i], bg[kk][j], acc[i][j], 0, 0, 0); \
} while (0)

    GEMM_STAGE(0, 0);
    for (int t = 0; t < 11; ++t) {
        int cur = t & 1;
        GEMM_STAGE(cur ^ 1, (t + 1) * 64);          // issue next tile first
        asm volatile("s_waitcnt vmcnt(8)" ::: "memory");   // cur landed; next 8 in flight
        __builtin_amdgcn_sched_barrier(0);
        __builtin_amdgcn_s_barrier();               // all waves' cur loads landed
        __builtin_amdgcn_sched_barrier(0);
        GEMM_COMPUTE(cur);
        __builtin_amdgcn_sched_barrier(0);
        __builtin_amdgcn_s_barrier();               // all reads of cur done -> safe to overwrite
        __builtin_amdgcn_sched_barrier(0);
    }
    asm volatile("s_waitcnt vmcnt(0)" ::: "memory");
    __builtin_amdgcn_sched_barrier(0);
    __builtin_amdgcn_s_barrier();
    __builtin_amdgcn_sched_barrier(0);
    GEMM_COMPUTE(1);

#undef GEMM_STAGE
#undef GEMM_COMPUTE

    // epilogue: C/D layout col=lane&15, row=(lane>>4)*4+reg
    const int cl = lane & 15, rb4 = (lane >> 4) * 4;
#pragma unroll
    for (int i = 0; i < 2; ++i)
#pragma unroll
        for (int j = 0; j < 4; ++j) {
            int col = bn + wc + j * 16 + cl;
            float b_ = bias[col];
#pragma unroll
            for (int r = 0; r < 4; ++r) {
                int row = bm + wr + i * 16 + rb4 + r;
                Ob[(size_t)row * GN + col] = f2bf(acc[i][j][r] + b_);
            }
        }

    // fold Vsum partials for V (z==2): per-lane 8-row sum, cross-group shfl, one atomic
    if (z == 2) {
        const int bb = bm >> 10;
#pragma unroll
        for (int j = 0; j < 4; ++j) {
            int col = bn + wc + j * 16 + cl;
            float s = bias[col] * 8.f;
#pragma unroll
            for (int i = 0; i < 2; ++i)
#pragma unroll
                for (int r = 0; r < 4; ++r) s += acc[i][j][r];
            s += __shfl_xor(s, 16, 64);
            s += __shfl_xor(s, 32, 64);
            if (hk == 0)
                atomicAdd(&Vsum[bb * EMB + col], s);
        }
    }
}

// ---------------- fused MFMA local attention + residual + layernorm ----------------
// (r13-verbatim) One block = (b, 16-query tile), 12 waves = 12 heads; x rows
// stashed in xs[] LDS, coalesced float4 LN-apply + store at the end.
__global__ __launch_bounds__(768, 3) void attn_ln(
    const u16* __restrict__ Qb, const u16* __restrict__ Kb, const u16* __restrict__ Vb,
    const float* __restrict__ Vsum, const float* __restrict__ am, const float* __restrict__ ww,
    const float* __restrict__ gamma, const float* __restrict__ beta, float* __restrict__ out)
{
    // XCD swizzle over 256 blocks: 32 contiguous per XCD
    int id = blockIdx.x + 64 * blockIdx.y;
    int swz = (id & 7) * 32 + (id >> 3);
    const int qt = swz & 63, b = swz >> 6;

    const int q0 = qt * QB;
    int kstart = q0 - WIN;
    if (kstart < 0) kstart = 0;
    if (kstart > SEQ - KB) kstart = SEQ - KB;

    const int h = threadIdx.x >> 6, lane = threadIdx.x & 63;
    const int fr = lane & 15, hk = lane >> 4;
    const int kof = hk * 8, rowg = hk * 4;

    __shared__ __align__(16) u16 Ps[NHEAD][QB][68];
    __shared__ __align__(16) float xs[QB][772];
    __shared__ float ps1[QB][13], ps2[QB][13];
    __shared__ float mu[QB], rs[QB];

    const float w0 = ww[0], w1 = ww[1], w2 = ww[2];

    // ---- fragments direct from global (bf16, L2-resident) ----
    bf16x8 aq[2], bk4[4][2], bv4[4][2];
    {
        const u16* qb = Qb + ((size_t)(b * SEQ + q0)) * EMB + h * HD;
#pragma unroll
        for (int kk = 0; kk < 2; ++kk)
            aq[kk] = *(const bf16x8*)(qb + (size_t)fr * EMB + kk * 32 + kof);
        const u16* kb = Kb + ((size_t)(b * SEQ + kstart)) * EMB + h * HD;
#pragma unroll
        for (int nj = 0; nj < 4; ++nj)
#pragma unroll
            for (int kk = 0; kk < 2; ++kk)
                bk4[nj][kk] = *(const bf16x8*)(kb + (size_t)(nj * 16 + fr) * EMB + kk * 32 + kof);
        // V^T gather: bv4[nj][kk][j] = V[kstart + kk*32+kof+j][h*64 + nj*16+fr]
        const u16* vb = Vb + ((size_t)(b * SEQ + kstart)) * EMB + h * HD;
#pragma unroll
        for (int nj = 0; nj < 4; ++nj)
#pragma unroll
            for (int kk = 0; kk < 2; ++kk) {
                union { bf16x8 v; u16 s[8]; } tmp;
#pragma unroll
                for (int j = 0; j < 8; ++j)
                    tmp.s[j] = vb[(size_t)(kk * 32 + kof + j) * EMB + nj * 16 + fr];
                bv4[nj][kk] = tmp.v;
            }
    }

    // ---- QK^T: 16x64 over K=64 ----
    f32x4 sc[4];
#pragma unroll
    for (int j = 0; j < 4; ++j) sc[j] = (f32x4){0.f, 0.f, 0.f, 0.f};
#pragma unroll
    for (int kk = 0; kk < 2; ++kk)
#pragma unroll
        for (int nj = 0; nj < 4; ++nj)
            sc[nj] = __builtin_amdgcn_mfma_f32_16x16x32_bf16(aq[kk], bk4[nj][kk], sc[nj], 0, 0, 0);

    // ---- per-row softmax over band + analytic uniform tail ----
    float amv[4];
#pragma unroll
    for (int nj = 0; nj < 4; ++nj) amv[nj] = am[b * SEQ + kstart + nj * 16 + fr];

    float t[4][4], cj[4][4], ua[4];
#pragma unroll
    for (int nj = 0; nj < 4; ++nj)
#pragma unroll
        for (int r = 0; r < 4; ++r) {
            int qrow = q0 + rowg + r;
            int kcol = kstart + nj * 16 + fr;
            int d = qrow - kcol; if (d < 0) d = -d;
            t[nj][r] = (d <= WIN) ? sc[nj][r] * 0.125f * amv[nj] : 0.f;
            cj[nj][r] = 0.f;
        }
#pragma unroll
    for (int r = 0; r < 4; ++r) ua[r] = 0.f;

#pragma unroll
    for (int it = 0; it < 3; ++it) {
        float wwi = it == 0 ? w0 : (it == 1 ? w1 : w2);
#pragma unroll
        for (int r = 0; r < 4; ++r) {
            float m = 0.f;   // out-of-tile zeros always present (SEQ > KB)
#pragma unroll
            for (int nj = 0; nj < 4; ++nj) m = fmaxf(m, t[nj][r]);
#pragma unroll
            for (int o = 1; o < 16; o <<= 1) m = fmaxf(m, __shfl_xor(m, o, 64));
            float e4[4], s = 0.f;
#pragma unroll
            for (int nj = 0; nj < 4; ++nj) { e4[nj] = __expf(t[nj][r] - m); s += e4[nj]; }
#pragma unroll
            for (int o = 1; o < 16; o <<= 1) s += __shfl_xor(s, o, 64);
            float un = __expf(-m);
            s += (float)(SEQ - KB) * un;
            float inv = wwi / s;
#pragma unroll
            for (int nj = 0; nj < 4; ++nj) cj[nj][r] += e4[nj] * inv;
            ua[r] += un * inv;
        }
        if (it < 2) {
#pragma unroll
            for (int nj = 0; nj < 4; ++nj)
#pragma unroll
                for (int r = 0; r < 4; ++r) t[nj][r] *= amv[nj];
        }
    }

    // ---- P' = cj - u -> LDS relayout (same-wave write->read, no barrier) ----
#pragma unroll
    for (int nj = 0; nj < 4; ++nj)
#pragma unroll
        for (int r = 0; r < 4; ++r)
            Ps[h][rowg + r][nj * 16 + fr] = f2bf(cj[nj][r] - ua[r]);

    // ---- PV: ctx = P' @ V (+ u * Vsum) ----
    f32x4 pv[4];
#pragma unroll
    for (int j = 0; j < 4; ++j) pv[j] = (f32x4){0.f, 0.f, 0.f, 0.f};
#pragma unroll
    for (int kk = 0; kk < 2; ++kk) {
        bf16x8 ap = *(const bf16x8*)&Ps[h][fr][kk * 32 + kof];
#pragma unroll
        for (int nj = 0; nj < 4; ++nj)
            pv[nj] = __builtin_amdgcn_mfma_f32_16x16x32_bf16(ap, bv4[nj][kk], pv[nj], 0, 0, 0);
    }

    // ---- x = residual(q) + ctx ; stash rows in xs for coalesced store ----
    float vs[4];
#pragma unroll
    for (int nj = 0; nj < 4; ++nj) vs[nj] = Vsum[b * EMB + h * HD + nj * 16 + fr];

    float xv[4][4];
#pragma unroll
    for (int nj = 0; nj < 4; ++nj)
#pragma unroll
        for (int r = 0; r < 4; ++r) {
            int row = q0 + rowg + r;
            float qres = bf2f(Qb[((size_t)(b * SEQ + row)) * EMB + h * HD + nj * 16 + fr]);
            xv[nj][r] = qres + pv[nj][r] + ua[r] * vs[nj];
            xs[rowg + r][h * HD + nj * 16 + fr] = xv[nj][r];
        }

    // ---- LN: per-head partial sums -> cross-wave reduce ----
    float s1r[4], s2r[4];
#pragma unroll
    for (int r = 0; r < 4; ++r) {
        float a = 0.f, c = 0.f;
#pragma unroll
        for (int nj = 0; nj < 4; ++nj) { a += xv[nj][r]; c += xv[nj][r] * xv[nj][r]; }
#pragma unroll
        for (int o = 1; o < 16; o <<= 1) { a += __shfl_xor(a, o, 64); c += __shfl_xor(c, o, 64); }
        s1r[r] = a; s2r[r] = c;
    }
    if (fr == 0) {
#pragma unroll
        for (int r = 0; r < 4; ++r) { ps1[rowg + r][h] = s1r[r]; ps2[rowg + r][h] = s2r[r]; }
    }
    __syncthreads();
    if (h == 0 && lane < QB) {
        float a = 0.f, c = 0.f;
#pragma unroll
        for (int w = 0; w < NHEAD; ++w) { a += ps1[lane][w]; c += ps2[lane][w]; }
        float mean = a * (1.f / EMB);
        float var = c * (1.f / EMB) - mean * mean;
        mu[lane] = mean;
        rs[lane] = rsqrtf(var + LN_EPS);
    }
    __syncthreads();

    // ---- coalesced LN-apply + store: thread t -> rows t/192 + {0,4,8,12} ----
    {
        const int tt = threadIdx.x;
        const int rbase = tt / 192, c4 = tt % 192;
        float4 g4 = *(const float4*)(gamma + c4 * 4);
        float4 b4 = *(const float4*)(beta + c4 * 4);
#pragma unroll
        for (int k4 = 0; k4 < 4; ++k4) {
            int row = rbase + k4 * 4;
            float4 x4 = *(const float4*)&xs[row][c4 * 4];
            float m_ = mu[row], r_ = rs[row];
            float4 o;
            o.x = g4.x * (x4.x - m_) * r_ + b4.x;
            o.y = g4.y * (x4.y - m_) * r_ + b4.y;
            o.z = g4.z * (x4.z - m_) * r_ + b4.z;
            o.w = g4.w * (x4.w - m_) * r_ + b4.w;
            *(float4*)(out + ((size_t)(b * SEQ + q0 + row)) * EMB + c4 * 4) = o;
        }
    }
}

// ---------------- launch ----------------
extern "C" void kernel_launch(void* const* d_in, const int* in_sizes, int n_in,
                              void* d_out, int out_size, void* d_ws, size_t ws_size,
                              hipStream_t stream)
{
    const float* q     = (const float*)d_in[0];
    const float* k     = (const float*)d_in[1];
    const float* v     = (const float*)d_in[2];
    const float* amask = (const float*)d_in[3];
    const float* Wq    = (const float*)d_in[4];
    const float* bq    = (const float*)d_in[5];
    const float* Wk    = (const float*)d_in[6];
    const float* bk    = (const float*)d_in[7];
    const float* Wv    = (const float*)d_in[8];
    const float* bv    = (const float*)d_in[9];
    const float* ww    = (const float*)d_in[10];
    const float* gamma = (const float*)d_in[11];
    const float* beta  = (const float*)d_in[12];
    float* out = (float*)d_out;

    char* ws = (char*)d_ws;
    u16*   Wbf  = (u16*)(ws);                    //  3,538,944 B
    u16*   Qbf  = (u16*)(ws + 3538944);          //  6,291,456 B
    u16*   Kbf  = (u16*)(ws + 9830400);          //  6,291,456 B
    u16*   Vbf  = (u16*)(ws + 16121856);         //  6,291,456 B
    float* Vsum = (float*)(ws + 22413312);       //     12,288 B

    hipLaunchKernelGGL(cast_w, dim3(1728), dim3(256), 0, stream,
                       Wq, Wk, Wv, Wbf, Vsum);
    hipLaunchKernelGGL(gemm_qkv, dim3(GN / 128, MROWS / 64, 3), dim3(256), 0, stream,
                       q, k, v, Wbf, bq, bk, bv, Qbf, Kbf, Vbf, Vsum);
    hipLaunchKernelGGL(attn_ln, dim3(SEQ / QB, NBAT), dim3(768), 0, stream,
                       Qbf, Kbf, Vbf, Vsum, amask, ww, gamma, beta, out);
}

// Round 16
// 55.819 us; speedup vs baseline: 1.2030x; 1.2030x over previous
//
#include <hip/hip_runtime.h>
#include <hip/hip_bf16.h>

#define EMB   768
#define SEQ   1024
#define NBAT  4
#define MROWS 4096      // NBAT*SEQ
#define NHEAD 12
#define HD    64
#define WIN   16
#define QB    16
#define KB    64
#define LN_EPS 1e-5f

typedef __attribute__((ext_vector_type(8))) short bf16x8;
typedef __attribute__((ext_vector_type(4))) float f32x4;
typedef unsigned short u16;
typedef unsigned int   u32;

// ---------------- f32 <-> bf16 helpers ----------------
static __device__ inline u16 f2bf(float f) {
    union { float f; u32 u; } a; a.f = f;
    u32 u = a.u;
    u32 r = (u + 0x7fffu + ((u >> 16) & 1u)) >> 16;
    return (u16)r;
}
static __device__ inline float bf2f(u16 x) {
    union { u32 u; float f; } c; c.u = ((u32)x) << 16; return c.f;
}

// ---------------- cast f32 -> bf16 (activations + weights) + Vsum zero ----------------
#define ACT4 786432u    // 4096*768/4
#define WT4  147456u    // 768*768/4
__global__ __launch_bounds__(256) void cast_all(
    const float* __restrict__ q, const float* __restrict__ k, const float* __restrict__ v,
    const float* __restrict__ wq, const float* __restrict__ wk, const float* __restrict__ wv,
    u16* __restrict__ Abf, u16* __restrict__ Wbf, float* __restrict__ Vsum)
{
    u32 u = blockIdx.x * 256u + threadIdx.x;
    if (u < NBAT * EMB) Vsum[u] = 0.f;           // re-zero each call (ws not re-poisoned)
    const float* src; u16* dst; u32 off;
    if (u < 3u * ACT4) {
        u32 which = u / ACT4;
        off = (u - which * ACT4) * 4u;
        src = which == 0 ? q : (which == 1 ? k : v);
        dst = Abf + (size_t)which * 3145728u + off;
    } else {
        u32 w2 = u - 3u * ACT4;
        u32 which = w2 / WT4;
        off = (w2 - which * WT4) * 4u;
        src = which == 0 ? wq : (which == 1 ? wk : wv);
        dst = Wbf + (size_t)which * 589824u + off;
    }
    float4 val = *(const float4*)(src + off);
    ushort4 o;
    o.x = f2bf(val.x); o.y = f2bf(val.y); o.z = f2bf(val.z); o.w = f2bf(val.w);
    *(ushort4*)dst = o;
}

// ---------------- bf16 MFMA GEMM: 64x128 tile, BK=64, dbuf + counted vmcnt ----------------
// (champion r10) 2-phase pipeline: issue STAGE(next) before COMPUTE(cur);
// s_waitcnt vmcnt(6) + raw s_barrier with sched_barrier(0) pins. XOR swizzle
// (slot ^= row&7) on the GLOBAL source and the ds_read address; linear LDS
// dest. z==2 epilogue folds Vsum partials via atomicAdd.
#define GK 768
#define GN 768

static __device__ inline void gload_lds16(const void* g, void* l) {
    __builtin_amdgcn_global_load_lds((const __attribute__((address_space(1))) void*)g,
                                     (__attribute__((address_space(3))) void*)l, 16, 0, 0);
}

__global__ __launch_bounds__(256) void gemm_qkv(
    const u16* __restrict__ Abase, const u16* __restrict__ Wbase,
    const float* __restrict__ bq, const float* __restrict__ bk, const float* __restrict__ bv,
    u16* __restrict__ Qb, u16* __restrict__ Kb, u16* __restrict__ Vb,
    float* __restrict__ Vsum)
{
    const int z = blockIdx.z;
    const u16* A = Abase + (size_t)z * (MROWS * GK);
    const u16* W = Wbase + (size_t)z * (GN * GK);
    const float* bias = (z == 0) ? bq : ((z == 1) ? bk : bv);
    u16* Ob = (z == 0) ? Qb : ((z == 1) ? Kb : Vb);

    // XCD swizzle: 384 tiles/z, 48 contiguous per XCD (8 A-panels each)
    int id = blockIdx.y * 6 + blockIdx.x;
    int swz = (id & 7) * 48 + (id >> 3);
    const int bm = (swz / 6) * 64, bn = (swz % 6) * 128;

    const int tid = threadIdx.x, wave = tid >> 6, lane = tid & 63;

    __shared__ __align__(16) u16 As[2][64 * 64];
    __shared__ __align__(16) u16 Bs[2][128 * 64];

    f32x4 acc[2][4];
#pragma unroll
    for (int i = 0; i < 2; ++i)
#pragma unroll
        for (int j = 0; j < 4; ++j) acc[i][j] = (f32x4){0.f, 0.f, 0.f, 0.f};

    const int wr = (wave >> 1) * 32, wc = (wave & 1) * 64;
    const int r0 = lane & 15, hk = lane >> 4;

    // staging indices: chunk c -> row = c>>3, src slot = (c&7)^(row&7)
    int arow[2], acol[2], brow[4], bcol[4];
#pragma unroll
    for (int j = 0; j < 2; ++j) {
        int c = j * 256 + tid;
        arow[j] = c >> 3;
        acol[j] = ((c & 7) ^ (arow[j] & 7)) * 8;
    }
#pragma unroll
    for (int j = 0; j < 4; ++j) {
        int c = j * 256 + tid;
        brow[j] = c >> 3;
        bcol[j] = ((c & 7) ^ (brow[j] & 7)) * 8;
    }

#define GEMM_STAGE(buf, K0) do { \
    _Pragma("unroll") for (int j = 0; j < 2; ++j) \
        gload_lds16(A + (size_t)(bm + arow[j]) * GK + (K0) + acol[j], \
                    &As[buf][(j * 256 + tid) * 8]); \
    _Pragma("unroll") for (int j = 0; j < 4; ++j) \
        gload_lds16(W + (size_t)(bn + brow[j]) * GK + (K0) + bcol[j], \
                    &Bs[buf][(j * 256 + tid) * 8]); \
} while (0)

#define GEMM_COMPUTE(buf) do { \
    bf16x8 af[2][2], bg[2][4]; \
    _Pragma("unroll") for (int kk = 0; kk < 2; ++kk) { \
        _Pragma("unroll") for (int i = 0; i < 2; ++i) { \
            int ra = wr + i * 16 + r0; int sa = (kk * 4 + hk) ^ (ra & 7); \
            af[kk][i] = *(const bf16x8*)&As[buf][ra * 64 + sa * 8]; } \
        _Pragma("unroll") for (int j = 0; j < 4; ++j) { \
            int rb = wc + j * 16 + r0; int sb = (kk * 4 + hk) ^ (rb & 7); \
            bg[kk][j] = *(const bf16x8*)&Bs[buf][rb * 64 + sb * 8]; } } \
    _Pragma("unroll") for (int kk = 0; kk < 2; ++kk) \
    _Pragma("unroll") for (int i = 0; i < 2; ++i) \
    _Pragma("unroll") for (int j = 0; j < 4; ++j) \
        acc[i][j] = __builtin_amdgcn_mfma_f32_16x16x32_bf16(af[kk][i], bg[kk][j], acc[i][j], 0, 0, 0); \
} while (0)

    GEMM_STAGE(0, 0);
    for (int t = 0; t < 11; ++t) {
        int cur = t & 1;
        GEMM_STAGE(cur ^ 1, (t + 1) * 64);          // issue next tile first
        asm volatile("s_waitcnt vmcnt(6)" ::: "memory");   // cur landed; next in flight
        __builtin_amdgcn_sched_barrier(0);
        __builtin_amdgcn_s_barrier();               // all waves' cur loads landed
        __builtin_amdgcn_sched_barrier(0);
        GEMM_COMPUTE(cur);
        __builtin_amdgcn_sched_barrier(0);
        __builtin_amdgcn_s_barrier();               // all reads of cur done -> safe to overwrite
        __builtin_amdgcn_sched_barrier(0);
    }
    asm volatile("s_waitcnt vmcnt(0)" ::: "memory");
    __builtin_amdgcn_sched_barrier(0);
    __builtin_amdgcn_s_barrier();
    __builtin_amdgcn_sched_barrier(0);
    GEMM_COMPUTE(1);

#undef GEMM_STAGE
#undef GEMM_COMPUTE

    // epilogue: C/D layout col=lane&15, row=(lane>>4)*4+reg
    const int cl = lane & 15, rb4 = (lane >> 4) * 4;
#pragma unroll
    for (int i = 0; i < 2; ++i)
#pragma unroll
        for (int j = 0; j < 4; ++j) {
            int col = bn + wc + j * 16 + cl;
            float b_ = bias[col];
#pragma unroll
            for (int r = 0; r < 4; ++r) {
                int row = bm + wr + i * 16 + rb4 + r;
                Ob[(size_t)row * GN + col] = f2bf(acc[i][j][r] + b_);
            }
        }

    // fold Vsum partials for V (z==2): per-lane 8-row sum, cross-group shfl, one atomic
    if (z == 2) {
        const int bb = bm >> 10;
#pragma unroll
        for (int j = 0; j < 4; ++j) {
            int col = bn + wc + j * 16 + cl;
            float s = bias[col] * 8.f;
#pragma unroll
            for (int i = 0; i < 2; ++i)
#pragma unroll
                for (int r = 0; r < 4; ++r) s += acc[i][j][r];
            s += __shfl_xor(s, 16, 64);
            s += __shfl_xor(s, 32, 64);
            if (hk == 0)
                atomicAdd(&Vsum[bb * EMB + col], s);
        }
    }
}

// ---------------- fused MFMA local attention + residual + layernorm ----------------
// (champion r10) One block = (b, 16-query tile), 12 waves = 12 heads.
__global__ __launch_bounds__(768, 3) void attn_ln(
    const u16* __restrict__ Qb, const u16* __restrict__ Kb, const u16* __restrict__ Vb,
    const float* __restrict__ Vsum, const float* __restrict__ am, const float* __restrict__ ww,
    const float* __restrict__ gamma, const float* __restrict__ beta, float* __restrict__ out)
{
    // XCD swizzle over 256 blocks: 32 contiguous per XCD
    int id = blockIdx.x + 64 * blockIdx.y;
    int swz = (id & 7) * 32 + (id >> 3);
    const int qt = swz & 63, b = swz >> 6;

    const int q0 = qt * QB;
    int kstart = q0 - WIN;
    if (kstart < 0) kstart = 0;
    if (kstart > SEQ - KB) kstart = SEQ - KB;

    const int h = threadIdx.x >> 6, lane = threadIdx.x & 63;
    const int fr = lane & 15, hk = lane >> 4;
    const int kof = hk * 8, rowg = hk * 4;

    __shared__ __align__(16) u16 Ps[NHEAD][QB][68];
    __shared__ float ps1[QB][13], ps2[QB][13];
    __shared__ float mu[QB], rs[QB];

    const float w0 = ww[0], w1 = ww[1], w2 = ww[2];

    // ---- fragments direct from global (bf16, L2-resident) ----
    bf16x8 aq[2], bk4[4][2], bv4[4][2];
    {
        const u16* qb = Qb + ((size_t)(b * SEQ + q0)) * EMB + h * HD;
#pragma unroll
        for (int kk = 0; kk < 2; ++kk)
            aq[kk] = *(const bf16x8*)(qb + (size_t)fr * EMB + kk * 32 + kof);
        const u16* kb = Kb + ((size_t)(b * SEQ + kstart)) * EMB + h * HD;
#pragma unroll
        for (int nj = 0; nj < 4; ++nj)
#pragma unroll
            for (int kk = 0; kk < 2; ++kk)
                bk4[nj][kk] = *(const bf16x8*)(kb + (size_t)(nj * 16 + fr) * EMB + kk * 32 + kof);
        // V^T gather: bv4[nj][kk][j] = V[kstart + kk*32+kof+j][h*64 + nj*16+fr]
        const u16* vb = Vb + ((size_t)(b * SEQ + kstart)) * EMB + h * HD;
#pragma unroll
        for (int nj = 0; nj < 4; ++nj)
#pragma unroll
            for (int kk = 0; kk < 2; ++kk) {
                union { bf16x8 v; u16 s[8]; } tmp;
#pragma unroll
                for (int j = 0; j < 8; ++j)
                    tmp.s[j] = vb[(size_t)(kk * 32 + kof + j) * EMB + nj * 16 + fr];
                bv4[nj][kk] = tmp.v;
            }
    }

    // ---- QK^T: 16x64 over K=64 ----
    f32x4 sc[4];
#pragma unroll
    for (int j = 0; j < 4; ++j) sc[j] = (f32x4){0.f, 0.f, 0.f, 0.f};
#pragma unroll
    for (int kk = 0; kk < 2; ++kk)
#pragma unroll
        for (int nj = 0; nj < 4; ++nj)
            sc[nj] = __builtin_amdgcn_mfma_f32_16x16x32_bf16(aq[kk], bk4[nj][kk], sc[nj], 0, 0, 0);

    // ---- per-row softmax over band + analytic uniform tail ----
    float amv[4];
#pragma unroll
    for (int nj = 0; nj < 4; ++nj) amv[nj] = am[b * SEQ + kstart + nj * 16 + fr];

    float t[4][4], cj[4][4], ua[4];
#pragma unroll
    for (int nj = 0; nj < 4; ++nj)
#pragma unroll
        for (int r = 0; r < 4; ++r) {
            int qrow = q0 + rowg + r;
            int kcol = kstart + nj * 16 + fr;
            int d = qrow - kcol; if (d < 0) d = -d;
            t[nj][r] = (d <= WIN) ? sc[nj][r] * 0.125f * amv[nj] : 0.f;
            cj[nj][r] = 0.f;
        }
#pragma unroll
    for (int r = 0; r < 4; ++r) ua[r] = 0.f;

#pragma unroll
    for (int it = 0; it < 3; ++it) {
        float wwi = it == 0 ? w0 : (it == 1 ? w1 : w2);
#pragma unroll
        for (int r = 0; r < 4; ++r) {
            float m = 0.f;   // out-of-tile zeros always present (SEQ > KB)
#pragma unroll
            for (int nj = 0; nj < 4; ++nj) m = fmaxf(m, t[nj][r]);
#pragma unroll
            for (int o = 1; o < 16; o <<= 1) m = fmaxf(m, __shfl_xor(m, o, 64));
            float e4[4], s = 0.f;
#pragma unroll
            for (int nj = 0; nj < 4; ++nj) { e4[nj] = __expf(t[nj][r] - m); s += e4[nj]; }
#pragma unroll
            for (int o = 1; o < 16; o <<= 1) s += __shfl_xor(s, o, 64);
            float un = __expf(-m);
            s += (float)(SEQ - KB) * un;
            float inv = wwi / s;
#pragma unroll
            for (int nj = 0; nj < 4; ++nj) cj[nj][r] += e4[nj] * inv;
            ua[r] += un * inv;
        }
        if (it < 2) {
#pragma unroll
            for (int nj = 0; nj < 4; ++nj)
#pragma unroll
                for (int r = 0; r < 4; ++r) t[nj][r] *= amv[nj];
        }
    }

    // ---- P' = cj - u -> LDS relayout (same-wave write->read, no barrier) ----
#pragma unroll
    for (int nj = 0; nj < 4; ++nj)
#pragma unroll
        for (int r = 0; r < 4; ++r)
            Ps[h][rowg + r][nj * 16 + fr] = f2bf(cj[nj][r] - ua[r]);

    // ---- PV: ctx = P' @ V (+ u * Vsum) ----
    f32x4 pv[4];
#pragma unroll
    for (int j = 0; j < 4; ++j) pv[j] = (f32x4){0.f, 0.f, 0.f, 0.f};
#pragma unroll
    for (int kk = 0; kk < 2; ++kk) {
        bf16x8 ap = *(const bf16x8*)&Ps[h][fr][kk * 32 + kof];
#pragma unroll
        for (int nj = 0; nj < 4; ++nj)
            pv[nj] = __builtin_amdgcn_mfma_f32_16x16x32_bf16(ap, bv4[nj][kk], pv[nj], 0, 0, 0);
    }

    // ---- x = residual(q) + ctx ----
    float vs[4];
#pragma unroll
    for (int nj = 0; nj < 4; ++nj) vs[nj] = Vsum[b * EMB + h * HD + nj * 16 + fr];

    float xv[4][4];
#pragma unroll
    for (int nj = 0; nj < 4; ++nj)
#pragma unroll
        for (int r = 0; r < 4; ++r) {
            int row = q0 + rowg + r;
            float qres = bf2f(Qb[((size_t)(b * SEQ + row)) * EMB + h * HD + nj * 16 + fr]);
            xv[nj][r] = qres + pv[nj][r] + ua[r] * vs[nj];
        }

    // ---- LN: per-head partial sums -> cross-wave reduce -> apply ----
    float s1r[4], s2r[4];
#pragma unroll
    for (int r = 0; r < 4; ++r) {
        float a = 0.f, c = 0.f;
#pragma unroll
        for (int nj = 0; nj < 4; ++nj) { a += xv[nj][r]; c += xv[nj][r] * xv[nj][r]; }
#pragma unroll
        for (int o = 1; o < 16; o <<= 1) { a += __shfl_xor(a, o, 64); c += __shfl_xor(c, o, 64); }
        s1r[r] = a; s2r[r] = c;
    }
    if (fr == 0) {
#pragma unroll
        for (int r = 0; r < 4; ++r) { ps1[rowg + r][h] = s1r[r]; ps2[rowg + r][h] = s2r[r]; }
    }
    __syncthreads();
    if (h == 0 && lane < QB) {
        float a = 0.f, c = 0.f;
#pragma unroll
        for (int w = 0; w < NHEAD; ++w) { a += ps1[lane][w]; c += ps2[lane][w]; }
        float mean = a * (1.f / EMB);
        float var = c * (1.f / EMB) - mean * mean;
        mu[lane] = mean;
        rs[lane] = rsqrtf(var + LN_EPS);
    }
    __syncthreads();

#pragma unroll
    for (int nj = 0; nj < 4; ++nj) {
        int col = h * HD + nj * 16 + fr;
        float g = gamma[col], be = beta[col];
#pragma unroll
        for (int r = 0; r < 4; ++r) {
            int row = q0 + rowg + r;
            out[((size_t)(b * SEQ + row)) * EMB + col] =
                g * (xv[nj][r] - mu[rowg + r]) * rs[rowg + r] + be;
        }
    }
}

// ---------------- launch ----------------
extern "C" void kernel_launch(void* const* d_in, const int* in_sizes, int n_in,
                              void* d_out, int out_size, void* d_ws, size_t ws_size,
                              hipStream_t stream)
{
    const float* q     = (const float*)d_in[0];
    const float* k     = (const float*)d_in[1];
    const float* v     = (const float*)d_in[2];
    const float* amask = (const float*)d_in[3];
    const float* Wq    = (const float*)d_in[4];
    const float* bq    = (const float*)d_in[5];
    const float* Wk    = (const float*)d_in[6];
    const float* bk    = (const float*)d_in[7];
    const float* Wv    = (const float*)d_in[8];
    const float* bv    = (const float*)d_in[9];
    const float* ww    = (const float*)d_in[10];
    const float* gamma = (const float*)d_in[11];
    const float* beta  = (const float*)d_in[12];
    float* out = (float*)d_out;

    char* ws = (char*)d_ws;
    u16*   Abf  = (u16*)(ws);                    // 18,874,368 B
    u16*   Wbf  = (u16*)(ws + 18874368);         //  3,538,944 B
    u16*   Qbf  = (u16*)(ws + 22413312);         //  6,291,456 B
    u16*   Kbf  = (u16*)(ws + 28704768);         //  6,291,456 B
    u16*   Vbf  = (u16*)(ws + 34996224);         //  6,291,456 B
    float* Vsum = (float*)(ws + 41287680);       //     12,288 B

    hipLaunchKernelGGL(cast_all, dim3(10944), dim3(256), 0, stream,
                       q, k, v, Wq, Wk, Wv, Abf, Wbf, Vsum);
    hipLaunchKernelGGL(gemm_qkv, dim3(GN / 128, MROWS / 64, 3), dim3(256), 0, stream,
                       Abf, Wbf, bq, bk, bv, Qbf, Kbf, Vbf, Vsum);
    hipLaunchKernelGGL(attn_ln, dim3(SEQ / QB, NBAT), dim3(768), 0, stream,
                       Qbf, Kbf, Vbf, Vsum, amask, ww, gamma, beta, out);
}